// Round 10
// baseline (2501.788 us; speedup 1.0000x reference)
//
#include <hip/hip_runtime.h>

// GRU encoder: B=64, T=512, F=64, H=256, D=64.
//   k1: xproj MFMA GEMM (R9, kept).
//   k2: Round-10 delta vs R9 scan: part2 stride-6 buffer -> flat 768-float
//       double-buffered LDS with ds_add_f32 accumulation (atomicAdd).
//       - matvec writes: conflict-free stride-1 (was 4-way aliased; 3.1M
//         bank-conflict cycles measured) and summed in-place.
//       - gate phase: 3 scalar reads, no 12-read gather, no 9-add tree ->
//         shorter serial chain that 15/16 waves wait on.
//       - idle threads (tid>=256) zero the next-step buffer during the
//         gate phase (1 write each, off critical path).
//       Everything else identical to the measured-best R9 structure.

typedef _Float16 half2_t __attribute__((ext_vector_type(2)));
typedef _Float16 f16x4_t __attribute__((ext_vector_type(4)));
typedef _Float16 f16x8_t __attribute__((ext_vector_type(8)));
typedef float f32x4_t __attribute__((ext_vector_type(4)));

#define LOG2E 1.4426950408889634f

__device__ __forceinline__ float fast_sigmoid(float x) {
  float e = __builtin_amdgcn_exp2f(-x * LOG2E);
  return __builtin_amdgcn_rcpf(1.0f + e);
}
__device__ __forceinline__ float fast_tanh(float x) {
  float e = __builtin_amdgcn_exp2f(x * (2.0f * LOG2E));
  return 1.0f - 2.0f * __builtin_amdgcn_rcpf(1.0f + e);
}

// ---------------------------------------------------------------------------
// Kernel 1: xproj GEMM via MFMA. C(32768x768) = A(32768x64) @ B(64x768) + b.
// (unchanged from round 9)
// ---------------------------------------------------------------------------
__global__ __launch_bounds__(256) void xproj_gemm(
    const float* __restrict__ x, const float* __restrict__ kmat,
    const float* __restrict__ bias, _Float16* __restrict__ xp) {
  const int tid = threadIdx.x;
  const int lane = tid & 63;
  const int w = tid >> 6;   // wave 0..3
  const int q = lane >> 4;  // k-subgroup 0..3
  const int r15 = lane & 15;
  const int rb = blockIdx.x * 128;
  const int cb = blockIdx.y * 128;

  // B-fragments: bf[nt][kt][j] = kmat[kt*32+q*8+j][cb+nt*16+r15].
  f16x8_t bf[8][2];
#pragma unroll
  for (int nt = 0; nt < 8; ++nt)
#pragma unroll
    for (int kt = 0; kt < 2; ++kt) {
      const float* bp =
          kmat + (size_t)(kt * 32 + q * 8) * 768 + cb + nt * 16 + r15;
      f16x8_t v;
#pragma unroll
      for (int j = 0; j < 8; ++j) v[j] = (_Float16)bp[(size_t)j * 768];
      bf[nt][kt] = v;
    }

  // A-fragments: af[mt][kt][j] = x[rb+w*32+mt*16+r15][kt*32+q*8+j].
  f16x8_t af[2][2];
#pragma unroll
  for (int mt = 0; mt < 2; ++mt)
#pragma unroll
    for (int kt = 0; kt < 2; ++kt) {
      const float* ap =
          x + (size_t)(rb + w * 32 + mt * 16 + r15) * 64 + kt * 32 + q * 8;
      float4 v0 = *(const float4*)(ap);
      float4 v1 = *(const float4*)(ap + 4);
      f16x8_t v;
      v[0] = (_Float16)v0.x; v[1] = (_Float16)v0.y;
      v[2] = (_Float16)v0.z; v[3] = (_Float16)v0.w;
      v[4] = (_Float16)v1.x; v[5] = (_Float16)v1.y;
      v[6] = (_Float16)v1.z; v[7] = (_Float16)v1.w;
      af[mt][kt] = v;
    }

  float bz[8];
#pragma unroll
  for (int nt = 0; nt < 8; ++nt) bz[nt] = bias[cb + nt * 16 + r15];

#pragma unroll
  for (int mt = 0; mt < 2; ++mt)
#pragma unroll
    for (int nt = 0; nt < 8; ++nt) {
      f32x4_t acc = {0.f, 0.f, 0.f, 0.f};
      acc = __builtin_amdgcn_mfma_f32_16x16x32_f16(af[mt][0], bf[nt][0], acc,
                                                   0, 0, 0);
      acc = __builtin_amdgcn_mfma_f32_16x16x32_f16(af[mt][1], bf[nt][1], acc,
                                                   0, 0, 0);
      // D: lane l reg r -> row rb+w*32+mt*16+q*4+r, col cb+nt*16+r15.
      _Float16* dp =
          xp + (size_t)(rb + w * 32 + mt * 16 + q * 4) * 768 + cb + nt * 16 +
          r15;
#pragma unroll
      for (int r = 0; r < 4; ++r)
        dp[(size_t)r * 768] = (_Float16)(acc[r] + bz[nt]);
    }
}

// ---------------------------------------------------------------------------
// Kernel 2: GRU scan. One block per batch row. 1024 threads = 16 waves.
// Thread (c = tid>>8, col = tid&255) holds W_rec[k in 64c..64c+63] for
// columns {col, col+256, col+512} as 96 packed f16 pairs. Gates on waves
// 0-3 only. Partials: ds_add_f32 into flat double-buffered p0/p1[768]
// (stride-1, conflict-free); idle waves zero the other buffer in the gate
// phase. 2-step manual unroll for static buffer selection.
// ---------------------------------------------------------------------------
__global__ __launch_bounds__(1024, 4) void gru_scan(
    const _Float16* __restrict__ xp, const float* __restrict__ wr,
    const float* __restrict__ dw, const float* __restrict__ db,
    float* __restrict__ out, float* __restrict__ state) {
  __shared__ float p0[768];  // partial/total sums, double-buffered
  __shared__ float p1[768];
  __shared__ float hbuf[256];
  __shared__ alignas(16) _Float16 hhalf[256];

  const int tid = threadIdx.x;
  const int b = blockIdx.x;
  const int c = tid >> 8;     // k-chunk 0..3
  const int col = tid & 255;  // output column within gate

  // --- load W_rec fragment as f16 pairs.
  half2_t w2[3][32];
#pragma unroll
  for (int q = 0; q < 3; ++q) {
    const float* wp = wr + (size_t)(c * 64) * 768 + col + q * 256;
#pragma unroll
    for (int j = 0; j < 32; ++j) {
      float wa = wp[(size_t)(2 * j) * 768];
      float wb = wp[(size_t)(2 * j + 1) * 768];
      half2_t p;
      p[0] = (_Float16)wa;
      p[1] = (_Float16)wb;
      w2[q][j] = p;
    }
  }
#pragma unroll
  for (int q = 0; q < 3; ++q)
#pragma unroll
    for (int j = 0; j < 32; ++j) asm volatile("" : "+v"(w2[q][j]));

  if (tid < 256) hhalf[tid] = (_Float16)0.0f;
  if (tid < 768) p0[tid] = 0.0f;  // buffer for step 0
  __syncthreads();

  const _Float16* xpb = xp + (size_t)b * 512 * 768;
  float* outb = out + (size_t)b * 512 * 256;
  const int4* hp2 = (const int4*)hhalf + c * 8;
  float hprev = 0.0f;

  // One GRU step. PACC: pre-zeroed buffer this step accumulates into and
  // gates read from. PZRO: buffer zeroed (by idle waves) for step T+1.
#define GSTEP(T, PACC, PZRO)                                              \
  {                                                                       \
    _Float16 x0 = (_Float16)0.0f, x1 = (_Float16)0.0f, x2 = (_Float16)0.0f; \
    if (tid < 256) {                                                      \
      if ((T)) outb[(size_t)((T)-1) * 256 + tid] = hprev;                 \
      const _Float16* xr = xpb + (size_t)(T)*768 + tid;                   \
      x0 = xr[0];                                                         \
      x1 = xr[256];                                                       \
      x2 = xr[512];                                                       \
    }                                                                     \
    float a0 = 0.0f, a1 = 0.0f, a2 = 0.0f;                                \
    _Pragma("unroll") for (int g = 0; g < 8; ++g) {                       \
      int4 hv = hp2[g]; /* wave-uniform broadcast read */                 \
      half2_t q0 = __builtin_bit_cast(half2_t, hv.x);                     \
      half2_t q1 = __builtin_bit_cast(half2_t, hv.y);                     \
      half2_t q2 = __builtin_bit_cast(half2_t, hv.z);                     \
      half2_t q3 = __builtin_bit_cast(half2_t, hv.w);                     \
      a0 = __builtin_amdgcn_fdot2(q0, w2[0][g * 4 + 0], a0, false);       \
      a0 = __builtin_amdgcn_fdot2(q1, w2[0][g * 4 + 1], a0, false);       \
      a0 = __builtin_amdgcn_fdot2(q2, w2[0][g * 4 + 2], a0, false);       \
      a0 = __builtin_amdgcn_fdot2(q3, w2[0][g * 4 + 3], a0, false);       \
      a1 = __builtin_amdgcn_fdot2(q0, w2[1][g * 4 + 0], a1, false);       \
      a1 = __builtin_amdgcn_fdot2(q1, w2[1][g * 4 + 1], a1, false);       \
      a1 = __builtin_amdgcn_fdot2(q2, w2[1][g * 4 + 2], a1, false);       \
      a1 = __builtin_amdgcn_fdot2(q3, w2[1][g * 4 + 3], a1, false);       \
      a2 = __builtin_amdgcn_fdot2(q0, w2[2][g * 4 + 0], a2, false);       \
      a2 = __builtin_amdgcn_fdot2(q1, w2[2][g * 4 + 1], a2, false);       \
      a2 = __builtin_amdgcn_fdot2(q2, w2[2][g * 4 + 2], a2, false);       \
      a2 = __builtin_amdgcn_fdot2(q3, w2[2][g * 4 + 3], a2, false);       \
    }                                                                     \
    atomicAdd(&PACC[col], a0);                                            \
    atomicAdd(&PACC[col + 256], a1);                                      \
    atomicAdd(&PACC[col + 512], a2);                                      \
    __syncthreads();                                                      \
    if (tid < 256) {                                                      \
      float rz = PACC[tid];                                               \
      float rr = PACC[256 + tid];                                         \
      float rh = PACC[512 + tid];                                         \
      float z = fast_sigmoid((float)x0 + rz);                             \
      float r = fast_sigmoid((float)x1 + rr);                             \
      float hh = fast_tanh((float)x2 + r * rh);                           \
      float hnew = z * hprev + (1.0f - z) * hh;                           \
      hprev = hnew;                                                       \
      hhalf[tid] = (_Float16)hnew;                                        \
    } else {                                                              \
      PZRO[tid - 256] = 0.0f; /* idle waves prep next buffer */           \
    }                                                                     \
    __syncthreads();                                                      \
  }

#pragma unroll 1
  for (int tt = 0; tt < 512; tt += 2) {
    GSTEP(tt, p0, p1)
    GSTEP(tt + 1, p1, p0)
  }
#undef GSTEP

  if (tid < 256) {
    outb[(size_t)511 * 256 + tid] = hprev;
    hbuf[tid] = hprev;
  }
  __syncthreads();

  // --- dense head: state[b,:] = tanh(h_last @ dense_w + dense_b)
  if (tid < 64) {
    float acc = db[tid];
#pragma unroll 8
    for (int k = 0; k < 256; ++k) acc = fmaf(hbuf[k], dw[k * 64 + tid], acc);
    state[(size_t)b * 64 + tid] = fast_tanh(acc);
  }
}

// ---------------------------------------------------------------------------
extern "C" void kernel_launch(void* const* d_in, const int* in_sizes, int n_in,
                              void* d_out, int out_size, void* d_ws,
                              size_t ws_size, hipStream_t stream) {
  const float* x = (const float*)d_in[0];     // (64,512,64)
  const float* kmat = (const float*)d_in[1];  // (64,768)
  const float* wr = (const float*)d_in[2];    // (256,768)
  const float* bias = (const float*)d_in[3];  // (768,)
  const float* dw = (const float*)d_in[4];    // (256,64)
  const float* db = (const float*)d_in[5];    // (64,)

  float* out = (float*)d_out;                   // (64,512,256)
  float* state = out + (size_t)64 * 512 * 256;  // (64,64)
  _Float16* xp = (_Float16*)d_ws;               // 64*512*768 f16 = 48 MiB

  dim3 gg(32768 / 128, 768 / 128);
  xproj_gemm<<<gg, 256, 0, stream>>>(x, kmat, bias, xp);
  gru_scan<<<64, 1024, 0, stream>>>(xp, wr, dw, db, out, state);
}

// Round 11
// 678.421 us; speedup vs baseline: 3.6877x; 3.6877x over previous
//
#include <hip/hip_runtime.h>

// GRU encoder: B=64, T=512, F=64, H=256, D=64.
//   k1: xproj MFMA GEMM (R9, kept).
//   k2: Round-11 delta vs R9 scan (R10's LDS atomics reverted: 4.2x
//       regression, LDS atomic RMW serializes the recurrence).
//       Single change: inner MAC encoding v_dot2_f32_f16 (VOP3P, reads
//       AGPR-resident W, measured ~4cyc) -> v_dot2c_f32_f16 (VOP2
//       accumulate). VOP2 cannot address AGPRs -> W forced into VGPRs
//       (96 + ~27 live <= 128, still 16 waves/CU); tests whether the
//       ~4cyc cost is the VOP3P/AGPR path vs the f16 pipe itself.
//       Diagnostic: VGPR_Count must jump 64 -> ~120.

typedef _Float16 half2_t __attribute__((ext_vector_type(2)));
typedef _Float16 f16x4_t __attribute__((ext_vector_type(4)));
typedef _Float16 f16x8_t __attribute__((ext_vector_type(8)));
typedef float f32x4_t __attribute__((ext_vector_type(4)));

#define LOG2E 1.4426950408889634f

__device__ __forceinline__ float fast_sigmoid(float x) {
  float e = __builtin_amdgcn_exp2f(-x * LOG2E);
  return __builtin_amdgcn_rcpf(1.0f + e);
}
__device__ __forceinline__ float fast_tanh(float x) {
  float e = __builtin_amdgcn_exp2f(x * (2.0f * LOG2E));
  return 1.0f - 2.0f * __builtin_amdgcn_rcpf(1.0f + e);
}

// VOP2 accumulate dot2: acc.f32 += a.f16[0]*b.f16[0] + a.f16[1]*b.f16[1].
// VOP2 operands are VGPR-only -> compiler must keep b (weights) in VGPRs.
#define DOT2C(acc, a, b) \
  asm("v_dot2c_f32_f16 %0, %1, %2" : "+v"(acc) : "v"(a), "v"(b))

// ---------------------------------------------------------------------------
// Kernel 1: xproj GEMM via MFMA. C(32768x768) = A(32768x64) @ B(64x768) + b.
// (unchanged from round 9)
// ---------------------------------------------------------------------------
__global__ __launch_bounds__(256) void xproj_gemm(
    const float* __restrict__ x, const float* __restrict__ kmat,
    const float* __restrict__ bias, _Float16* __restrict__ xp) {
  const int tid = threadIdx.x;
  const int lane = tid & 63;
  const int w = tid >> 6;   // wave 0..3
  const int q = lane >> 4;  // k-subgroup 0..3
  const int r15 = lane & 15;
  const int rb = blockIdx.x * 128;
  const int cb = blockIdx.y * 128;

  // B-fragments: bf[nt][kt][j] = kmat[kt*32+q*8+j][cb+nt*16+r15].
  f16x8_t bf[8][2];
#pragma unroll
  for (int nt = 0; nt < 8; ++nt)
#pragma unroll
    for (int kt = 0; kt < 2; ++kt) {
      const float* bp =
          kmat + (size_t)(kt * 32 + q * 8) * 768 + cb + nt * 16 + r15;
      f16x8_t v;
#pragma unroll
      for (int j = 0; j < 8; ++j) v[j] = (_Float16)bp[(size_t)j * 768];
      bf[nt][kt] = v;
    }

  // A-fragments: af[mt][kt][j] = x[rb+w*32+mt*16+r15][kt*32+q*8+j].
  f16x8_t af[2][2];
#pragma unroll
  for (int mt = 0; mt < 2; ++mt)
#pragma unroll
    for (int kt = 0; kt < 2; ++kt) {
      const float* ap =
          x + (size_t)(rb + w * 32 + mt * 16 + r15) * 64 + kt * 32 + q * 8;
      float4 v0 = *(const float4*)(ap);
      float4 v1 = *(const float4*)(ap + 4);
      f16x8_t v;
      v[0] = (_Float16)v0.x; v[1] = (_Float16)v0.y;
      v[2] = (_Float16)v0.z; v[3] = (_Float16)v0.w;
      v[4] = (_Float16)v1.x; v[5] = (_Float16)v1.y;
      v[6] = (_Float16)v1.z; v[7] = (_Float16)v1.w;
      af[mt][kt] = v;
    }

  float bz[8];
#pragma unroll
  for (int nt = 0; nt < 8; ++nt) bz[nt] = bias[cb + nt * 16 + r15];

#pragma unroll
  for (int mt = 0; mt < 2; ++mt)
#pragma unroll
    for (int nt = 0; nt < 8; ++nt) {
      f32x4_t acc = {0.f, 0.f, 0.f, 0.f};
      acc = __builtin_amdgcn_mfma_f32_16x16x32_f16(af[mt][0], bf[nt][0], acc,
                                                   0, 0, 0);
      acc = __builtin_amdgcn_mfma_f32_16x16x32_f16(af[mt][1], bf[nt][1], acc,
                                                   0, 0, 0);
      // D: lane l reg r -> row rb+w*32+mt*16+q*4+r, col cb+nt*16+r15.
      _Float16* dp =
          xp + (size_t)(rb + w * 32 + mt * 16 + q * 4) * 768 + cb + nt * 16 +
          r15;
#pragma unroll
      for (int r = 0; r < 4; ++r)
        dp[(size_t)r * 768] = (_Float16)(acc[r] + bz[nt]);
    }
}

// ---------------------------------------------------------------------------
// Kernel 2: GRU scan (R9 structure). One block per batch row. 1024 threads
// = 16 waves. Thread (c = tid>>8, col = tid&255) holds W_rec[k in
// 64c..64c+63] for columns {col, col+256, col+512} as 96 packed f16 pairs
// (VGPR-forced by the VOP2 encoding). Gates on waves 0-3 only.
// part2 layout: row (gate*256+col), stride 6 floats, entry [c].
// ---------------------------------------------------------------------------
__global__ __launch_bounds__(1024, 4) void gru_scan(
    const _Float16* __restrict__ xp, const float* __restrict__ wr,
    const float* __restrict__ dw, const float* __restrict__ db,
    float* __restrict__ out, float* __restrict__ state) {
  __shared__ float2 part2[768 * 3];  // [(gate*256+col)*3 + pair], 18.4 KB
  __shared__ float hbuf[256];
  __shared__ alignas(16) _Float16 hhalf[256];

  const int tid = threadIdx.x;
  const int b = blockIdx.x;
  const int c = tid >> 8;     // k-chunk 0..3
  const int col = tid & 255;  // output column within gate

  // --- load W_rec fragment as f16 pairs.
  half2_t w2[3][32];
#pragma unroll
  for (int q = 0; q < 3; ++q) {
    const float* wp = wr + (size_t)(c * 64) * 768 + col + q * 256;
#pragma unroll
    for (int j = 0; j < 32; ++j) {
      float wa = wp[(size_t)(2 * j) * 768];
      float wb = wp[(size_t)(2 * j + 1) * 768];
      half2_t p;
      p[0] = (_Float16)wa;
      p[1] = (_Float16)wb;
      w2[q][j] = p;
    }
  }

  if (tid < 256) hhalf[tid] = (_Float16)0.0f;
  __syncthreads();

  const _Float16* xpb = xp + (size_t)b * 512 * 768;
  float* outb = out + (size_t)b * 512 * 256;
  const int4* hp2 = (const int4*)hhalf + c * 8;
  float* pw = (float*)part2;
  float hprev = 0.0f;

#pragma unroll 1
  for (int t = 0; t < 512; ++t) {
    // Gate waves only: deferred h(t-1) store + direct coalesced x loads.
    _Float16 x0 = (_Float16)0.0f, x1 = (_Float16)0.0f, x2 = (_Float16)0.0f;
    if (tid < 256) {
      if (t) outb[(size_t)(t - 1) * 256 + tid] = hprev;
      const _Float16* xr = xpb + (size_t)t * 768 + tid;
      x0 = xr[0];
      x1 = xr[256];
      x2 = xr[512];
    }

    float a0 = 0.0f, a1 = 0.0f, a2 = 0.0f;
#pragma unroll
    for (int g = 0; g < 8; ++g) {
      int4 hv = hp2[g];  // wave-uniform broadcast read
      half2_t p0 = __builtin_bit_cast(half2_t, hv.x);
      half2_t p1 = __builtin_bit_cast(half2_t, hv.y);
      half2_t p2 = __builtin_bit_cast(half2_t, hv.z);
      half2_t p3 = __builtin_bit_cast(half2_t, hv.w);
      DOT2C(a0, p0, w2[0][g * 4 + 0]);
      DOT2C(a0, p1, w2[0][g * 4 + 1]);
      DOT2C(a0, p2, w2[0][g * 4 + 2]);
      DOT2C(a0, p3, w2[0][g * 4 + 3]);
      DOT2C(a1, p0, w2[1][g * 4 + 0]);
      DOT2C(a1, p1, w2[1][g * 4 + 1]);
      DOT2C(a1, p2, w2[1][g * 4 + 2]);
      DOT2C(a1, p3, w2[1][g * 4 + 3]);
      DOT2C(a2, p0, w2[2][g * 4 + 0]);
      DOT2C(a2, p1, w2[2][g * 4 + 1]);
      DOT2C(a2, p2, w2[2][g * 4 + 2]);
      DOT2C(a2, p3, w2[2][g * 4 + 3]);
    }
    // Transposed partials: row = gate*256+col, stride 6 floats, entry c.
    pw[col * 6 + c] = a0;
    pw[1536 + col * 6 + c] = a1;
    pw[3072 + col * 6 + c] = a2;
    __syncthreads();

    // --- gates: waves 0..3 only.
    if (tid < 256) {
      const int i = tid;
      float2 z0 = part2[i * 3 + 0];
      float2 z1 = part2[i * 3 + 1];
      float2 r0 = part2[768 + i * 3 + 0];
      float2 r1 = part2[768 + i * 3 + 1];
      float2 h0 = part2[1536 + i * 3 + 0];
      float2 h1 = part2[1536 + i * 3 + 1];
      float rz = (z0.x + z0.y) + (z1.x + z1.y);
      float rr = (r0.x + r0.y) + (r1.x + r1.y);
      float rh = (h0.x + h0.y) + (h1.x + h1.y);
      float z = fast_sigmoid((float)x0 + rz);
      float r = fast_sigmoid((float)x1 + rr);
      float hh = fast_tanh((float)x2 + r * rh);
      float hnew = z * hprev + (1.0f - z) * hh;
      hprev = hnew;
      hhalf[i] = (_Float16)hnew;
    }
    __syncthreads();
  }

  if (tid < 256) {
    outb[(size_t)511 * 256 + tid] = hprev;
    hbuf[tid] = hprev;
  }
  __syncthreads();

  // --- dense head: state[b,:] = tanh(h_last @ dense_w + dense_b)
  if (tid < 64) {
    float acc = db[tid];
#pragma unroll 8
    for (int k = 0; k < 256; ++k) acc = fmaf(hbuf[k], dw[k * 64 + tid], acc);
    state[(size_t)b * 64 + tid] = fast_tanh(acc);
  }
}

// ---------------------------------------------------------------------------
extern "C" void kernel_launch(void* const* d_in, const int* in_sizes, int n_in,
                              void* d_out, int out_size, void* d_ws,
                              size_t ws_size, hipStream_t stream) {
  const float* x = (const float*)d_in[0];     // (64,512,64)
  const float* kmat = (const float*)d_in[1];  // (64,768)
  const float* wr = (const float*)d_in[2];    // (256,768)
  const float* bias = (const float*)d_in[3];  // (768,)
  const float* dw = (const float*)d_in[4];    // (256,64)
  const float* db = (const float*)d_in[5];    // (64,)

  float* out = (float*)d_out;                   // (64,512,256)
  float* state = out + (size_t)64 * 512 * 256;  // (64,64)
  _Float16* xp = (_Float16*)d_ws;               // 64*512*768 f16 = 48 MiB

  dim3 gg(32768 / 128, 768 / 128);
  xproj_gemm<<<gg, 256, 0, stream>>>(x, kmat, bias, xp);
  gru_scan<<<64, 1024, 0, stream>>>(xp, wr, dw, db, out, state);
}